// Round 7
// baseline (107.232 us; speedup 1.0000x reference)
//
#include <hip/hip_runtime.h>
#include <stdint.h>

// Bahdanau attention: B=64, T=2048, D=256, U=256, all fp32 in/out.
// out = [context (B*D) | attn (B*T)] flat fp32.
#define Bq 64
#define Tq 2048
#define Dq 256
#define Uq 256

typedef __bf16 bf16x8 __attribute__((ext_vector_type(8)));
typedef float f32x4 __attribute__((ext_vector_type(4)));

// A LDS: [row 0..127][hi oct0-3 (64B) | lo oct0-3 (64B) | 16B pad] -> stride 144
#define ARS 144
#define ABUFSZ (128 * ARS)   // 18432 B per buffer
// B LDS: [plane][oct 0..3][u 0..127][16B]
#define BPLSZ 8192
#define BBUFSZ (2 * BPLSZ)   // 16384 B per buffer

// split fp32 into truncated-bf16 hi + bf16(lo) residual. a = hi + lo + O(2^-16 |a|)
__device__ inline void split2(float a, unsigned short& h, unsigned short& l) {
  unsigned bits = __float_as_uint(a);
  h = (unsigned short)(bits >> 16);
  float hf = __uint_as_float(bits & 0xffff0000u);
  l = (unsigned short)(__float_as_uint(a - hf) >> 16);
}

// tanh(x) = 1 - 2/(exp(2x)+1). ~6 VALU ops, saturates correctly.
__device__ inline float fast_tanh(float x) {
  float e = __expf(2.0f * x);
  return 1.0f - 2.0f * __builtin_amdgcn_rcpf(e + 1.0f);
}

// K0: split w1 [U][D] fp32 -> bf16 hi/lo planes, stored OCTET-MAJOR:
// plane[(k>>3)*U*8 + u*8 + (k&7)]
__global__ void k0_split(const float* __restrict__ w1,
                         unsigned short* __restrict__ hi,
                         unsigned short* __restrict__ lo) {
  int idx = blockIdx.x * 256 + threadIdx.x;
  int i = idx * 4;
  int u = i >> 8;
  int k = i & 255;
  float4 v = *reinterpret_cast<const float4*>(&w1[i]);
  ushort4 h, l;
  split2(v.x, h.x, l.x);
  split2(v.y, h.y, l.y);
  split2(v.z, h.z, l.z);
  split2(v.w, h.w, l.w);
  int dst = (k >> 3) * (Uq * 8) + u * 8 + (k & 7);
  *reinterpret_cast<ushort4*>(&hi[dst]) = h;
  *reinterpret_cast<ushort4*>(&lo[dst]) = l;
}

// K1: comb[b][u] = dot(hidden[b], w2_w[u]) + w2_b[u] + w1_b[u]
__global__ void k1_comb(const float* __restrict__ hidden,
                        const float* __restrict__ w2_w,
                        const float* __restrict__ w2_b,
                        const float* __restrict__ w1_b,
                        float* __restrict__ comb) {
  int b = blockIdx.x;
  int wave = threadIdx.x >> 6;
  int lane = threadIdx.x & 63;
  int u = blockIdx.y * 4 + wave;
  const float* h = hidden + b * Dq;
  const float* w = w2_w + u * Dq;
  float sum = 0.f;
#pragma unroll
  for (int i = 0; i < Dq; i += 64) sum += h[lane + i] * w[lane + i];
#pragma unroll
  for (int m = 32; m >= 1; m >>= 1) sum += __shfl_xor(sum, m, 64);
  if (lane == 0) comb[b * Uq + u] = sum + w2_b[u] + w1_b[u];
}

// K2: partial score over a 128-u slice, 2-phase pipelined GEMM.
// spart[uq][b*T+t] = sum_{u in slice} v_w[u] * tanh(feat·w1[u] + comb[u])
// Block 256 thr = 4 waves (2x2); tile 128t x 128u; wave 64x64; K-chunk 32.
// B DMA'd to LDS one chunk ahead; A regs loaded two chunks ahead,
// split+written one chunk ahead. One barrier per chunk.
__global__ __launch_bounds__(256, 2) void k2_score(
    const float* __restrict__ feat, const unsigned short* __restrict__ w1hi,
    const unsigned short* __restrict__ w1lo, const float* __restrict__ comb,
    const float* __restrict__ v_w, float* __restrict__ spart) {
  __shared__ char sA[2 * ABUFSZ];
  __shared__ char sB[2 * BBUFSZ];
  __shared__ float scp[2][128];
  const int tid = threadIdx.x;
  const int w = tid >> 6;
  const int l = tid & 63;
  const int fr = l & 15;
  const int g = l >> 4;
  const int wr = w >> 1;
  const int wc = w & 1;
  const int r0 = blockIdx.x * 128;   // flat (b,t) row base
  const int u0 = blockIdx.y * 128;
  const int b = blockIdx.x >> 4;     // Tq/128 = 16 tiles per batch

  // A staging role: row = tid>>1, half h_ = tid&1 (cols h_*16..h_*16+15)
  const int arow = tid >> 1;
  const int ah_ = tid & 1;
  const float* aload = feat + (size_t)(r0 + arow) * Dq + ah_ * 16;
  char* const awbase = sA + arow * ARS + ah_ * 32;

  float4 pa[2][4];

  // ---- staging helpers ----
  auto issueA = [&](int ch) {
#pragma unroll
    for (int j = 0; j < 4; ++j)
      pa[ch & 1][j] =
          *reinterpret_cast<const float4*>(aload + ch * 32 + j * 4);
  };
  auto issueB = [&](int ch) {
    char* bbase = sB + (ch & 1) * BBUFSZ;
#pragma unroll
    for (int q = 0; q < 2; ++q) {
      int d = w * 2 + q;                       // 0..7
      int p = d >> 2;                          // plane
      int j = (d >> 1) & 1;                    // serves octs via 2KB halves
      // decompose d: p = d>>2? No: 8 DMAs for hi (4 oct x 2 halves) + 8 lo
      // => use d over 0..7 with q2 loop below instead.
      (void)p; (void)j;
    }
    // 16 DMAs total: wave w issues d = w*4..w*4+3
#pragma unroll
    for (int q = 0; q < 4; ++q) {
      int d = w * 4 + q;                       // 0..15
      int p = d >> 3;                          // 0=hi,1=lo
      int j = (d >> 1) & 3;                    // oct
      int h2 = d & 1;                          // u-half
      const unsigned short* src = (p ? w1lo : w1hi) +
          (size_t)(ch * 4 + j) * (Uq * 8) + u0 * 8 + h2 * 512 + l * 8;
      char* dst = bbase + p * BPLSZ + j * 2048 + h2 * 1024;
      __builtin_amdgcn_global_load_lds(
          (const __attribute__((address_space(1))) unsigned int*)src,
          (__attribute__((address_space(3))) unsigned int*)dst, 16, 0, 0);
    }
  };
  auto splitWrite = [&](int ch) {
    const float4& v0 = pa[ch & 1][0];
    const float4& v1 = pa[ch & 1][1];
    const float4& v2 = pa[ch & 1][2];
    const float4& v3 = pa[ch & 1][3];
    float f[16] = {v0.x, v0.y, v0.z, v0.w, v1.x, v1.y, v1.z, v1.w,
                   v2.x, v2.y, v2.z, v2.w, v3.x, v3.y, v3.z, v3.w};
    unsigned short h[16], lo16[16];
#pragma unroll
    for (int j = 0; j < 16; ++j) split2(f[j], h[j], lo16[j]);
    uint4 H0, H1, L0, L1;
    H0.x = h[0] | (h[1] << 16);   H0.y = h[2] | (h[3] << 16);
    H0.z = h[4] | (h[5] << 16);   H0.w = h[6] | (h[7] << 16);
    H1.x = h[8] | (h[9] << 16);   H1.y = h[10] | (h[11] << 16);
    H1.z = h[12] | (h[13] << 16); H1.w = h[14] | (h[15] << 16);
    L0.x = lo16[0] | (lo16[1] << 16);   L0.y = lo16[2] | (lo16[3] << 16);
    L0.z = lo16[4] | (lo16[5] << 16);   L0.w = lo16[6] | (lo16[7] << 16);
    L1.x = lo16[8] | (lo16[9] << 16);   L1.y = lo16[10] | (lo16[11] << 16);
    L1.z = lo16[12] | (lo16[13] << 16); L1.w = lo16[14] | (lo16[15] << 16);
    char* d = awbase + (ch & 1) * ABUFSZ;
    *reinterpret_cast<uint4*>(d) = H0;
    *reinterpret_cast<uint4*>(d + 16) = H1;
    *reinterpret_cast<uint4*>(d + 64) = L0;
    *reinterpret_cast<uint4*>(d + 80) = L1;
  };

  f32x4 acc[4][4] = {};

  // ---- prologue ----
  issueA(0);
  issueB(0);
  issueA(1);
  splitWrite(0);
  issueB(1);
  __syncthreads();

  // ---- main loop: one barrier per chunk ----
#pragma unroll
  for (int c = 0; c < 8; ++c) {
    if (c < 6) issueA(c + 2);
    if (c < 7) {
      splitWrite(c + 1);
      issueB(c + 1);
    }
    {
      char* bA = sA + (c & 1) * ABUFSZ;
      char* bB = sB + (c & 1) * BBUFSZ;
      bf16x8 ahv[4], alv[4], bhv[4], blv[4];
#pragma unroll
      for (int mf = 0; mf < 4; ++mf) {
        const char* r = bA + (wr * 64 + mf * 16 + fr) * ARS + g * 16;
        ahv[mf] = *reinterpret_cast<const bf16x8*>(r);
        alv[mf] = *reinterpret_cast<const bf16x8*>(r + 64);
      }
#pragma unroll
      for (int nf = 0; nf < 4; ++nf) {
        const char* r = bB + g * 2048 + (wc * 64 + nf * 16 + fr) * 16;
        bhv[nf] = *reinterpret_cast<const bf16x8*>(r);
        blv[nf] = *reinterpret_cast<const bf16x8*>(r + BPLSZ);
      }
#pragma unroll
      for (int mf = 0; mf < 4; ++mf) {
#pragma unroll
        for (int nf = 0; nf < 4; ++nf) {
          acc[mf][nf] = __builtin_amdgcn_mfma_f32_16x16x32_bf16(
              ahv[mf], bhv[nf], acc[mf][nf], 0, 0, 0);
          acc[mf][nf] = __builtin_amdgcn_mfma_f32_16x16x32_bf16(
              ahv[mf], blv[nf], acc[mf][nf], 0, 0, 0);
          acc[mf][nf] = __builtin_amdgcn_mfma_f32_16x16x32_bf16(
              alv[mf], bhv[nf], acc[mf][nf], 0, 0, 0);
        }
      }
    }
    if (c < 7) __syncthreads();
  }

  // ---- epilogue: tanh + v-dot; acc[mf][nf][r] is
  // (t_local = wr*64 + mf*16 + g*4 + r, u = u0 + wc*64 + nf*16 + fr) ----
  float cb[4], vw4[4];
#pragma unroll
  for (int nf = 0; nf < 4; ++nf) {
    int u = u0 + wc * 64 + nf * 16 + fr;
    cb[nf] = comb[b * Uq + u];
    vw4[nf] = v_w[u];
  }
  float sc[4][4];
#pragma unroll
  for (int mf = 0; mf < 4; ++mf)
#pragma unroll
    for (int r = 0; r < 4; ++r) sc[mf][r] = 0.f;
#pragma unroll
  for (int mf = 0; mf < 4; ++mf)
#pragma unroll
    for (int nf = 0; nf < 4; ++nf)
#pragma unroll
      for (int r = 0; r < 4; ++r)
        sc[mf][r] += vw4[nf] * fast_tanh(acc[mf][nf][r] + cb[nf]);
#pragma unroll
  for (int m = 1; m < 16; m <<= 1)
#pragma unroll
    for (int mf = 0; mf < 4; ++mf)
#pragma unroll
      for (int r = 0; r < 4; ++r) sc[mf][r] += __shfl_xor(sc[mf][r], m, 16);
  __syncthreads();  // re-use scp safely after main loop
  if (fr == 0) {
#pragma unroll
    for (int mf = 0; mf < 4; ++mf)
#pragma unroll
      for (int r = 0; r < 4; ++r)
        scp[wc][wr * 64 + mf * 16 + g * 4 + r] = sc[mf][r];
  }
  __syncthreads();
  if (tid < 128)
    spart[(size_t)blockIdx.y * (Bq * Tq) + r0 + tid] =
        scp[0][tid] + scp[1][tid];
}

// K3: softmax over T per batch; reduces the 2 u-slice partials + v_b first.
__global__ void k3_softmax(const float* __restrict__ spart,
                           const float* __restrict__ v_b,
                           float* __restrict__ s) {
  int b = blockIdx.x;
  int tid = threadIdx.x;
  const int base = b * Tq;
  const int P = Bq * Tq;
  float vb = v_b[0];
  float v[8];
  float m = -1e30f;
#pragma unroll
  for (int i = 0; i < 8; ++i) {
    int idx = base + tid + 256 * i;
    v[i] = spart[idx] + spart[P + idx] + vb;
    m = fmaxf(m, v[i]);
  }
#pragma unroll
  for (int mk = 32; mk >= 1; mk >>= 1) m = fmaxf(m, __shfl_xor(m, mk, 64));
  __shared__ float red[4];
  int wv = tid >> 6, ln = tid & 63;
  if (ln == 0) red[wv] = m;
  __syncthreads();
  m = fmaxf(fmaxf(red[0], red[1]), fmaxf(red[2], red[3]));
  __syncthreads();
  float sum = 0.f;
#pragma unroll
  for (int i = 0; i < 8; ++i) {
    v[i] = __expf(v[i] - m);
    sum += v[i];
  }
#pragma unroll
  for (int mk = 32; mk >= 1; mk >>= 1) sum += __shfl_xor(sum, mk, 64);
  if (ln == 0) red[wv] = sum;
  __syncthreads();
  sum = red[0] + red[1] + red[2] + red[3];
  float inv = 1.f / sum;
#pragma unroll
  for (int i = 0; i < 8; ++i) s[base + tid + 256 * i] = v[i] * inv;
}

// K4a: partial context over a 256-t slice
__global__ void k4_partial(const float* __restrict__ feat,
                           const float* __restrict__ attn,
                           float* __restrict__ part) {
  int b = blockIdx.x;
  int ts = blockIdx.y;
  int d = threadIdx.x;
  const int t0 = ts * 256;
  const float* f = feat + ((size_t)(b * Tq + t0)) * Dq + d;
  const float* a = attn + b * Tq + t0;
  float acc = 0.f;
#pragma unroll 8
  for (int t = 0; t < 256; ++t) acc += a[t] * f[(size_t)t * Dq];
  part[(b * 8 + ts) * Dq + d] = acc;
}

// K4b: reduce the 8 partials
__global__ void k4_reduce(const float* __restrict__ part,
                          float* __restrict__ ctx) {
  int b = blockIdx.x;
  int d = threadIdx.x;
  float s = 0.f;
#pragma unroll
  for (int ts = 0; ts < 8; ++ts) s += part[(b * 8 + ts) * Dq + d];
  ctx[b * Dq + d] = s;
}

extern "C" void kernel_launch(void* const* d_in, const int* in_sizes, int n_in,
                              void* d_out, int out_size, void* d_ws,
                              size_t ws_size, hipStream_t stream) {
  const float* feat   = (const float*)d_in[0];
  const float* hidden = (const float*)d_in[1];
  const float* w1_w   = (const float*)d_in[2];
  const float* w1_b   = (const float*)d_in[3];
  const float* w2_w   = (const float*)d_in[4];
  const float* w2_b   = (const float*)d_in[5];
  const float* v_w    = (const float*)d_in[6];
  const float* v_b    = (const float*)d_in[7];

  float* ctx  = (float*)d_out;             // [B][D]
  float* attn = ctx + Bq * Dq;             // [B][T]
  float* comb = (float*)d_ws;              // [B][U]        64 KB
  float* part = comb + Bq * Uq;            // [B][8][D]     512 KB
  float* spart = part + Bq * 8 * Dq;       // [2][B][T]     1 MB
  unsigned short* w1hi = (unsigned short*)(spart + 2 * Bq * Tq);  // 128 KB
  unsigned short* w1lo = w1hi + Uq * Dq;                          // 128 KB

  k0_split<<<Uq * Dq / 1024, 256, 0, stream>>>(w1_w, w1hi, w1lo);
  k1_comb<<<dim3(Bq, Uq / 4), 256, 0, stream>>>(hidden, w2_w, w2_b, w1_b, comb);
  k2_score<<<dim3(Tq * Bq / 128, 2), 256, 0, stream>>>(feat, w1hi, w1lo, comb,
                                                       v_w, spart);
  k3_softmax<<<Bq, 256, 0, stream>>>(spart, v_b, attn);
  k4_partial<<<dim3(Bq, 8), 256, 0, stream>>>(feat, attn, part);
  k4_reduce<<<Bq, 256, 0, stream>>>(part, ctx);
}